// Round 9
// baseline (414.865 us; speedup 1.0000x reference)
//
#include <hip/hip_runtime.h>

// Problem constants (from reference)
constexpr int N_NODES = 100000;
constexpr int N_EDGES = 1000000;
constexpr int D_NODE  = 64;
constexpr int D_EDGE  = 32;
constexpr int D_GLOB  = 32;
constexpr int OUT_DIM = 64;
constexpr int K1 = 2*D_NODE + D_EDGE + D_GLOB; // 192
constexpr int K2 = D_NODE + OUT_DIM + D_GLOB;  // 160

typedef _Float16 f16x8 __attribute__((ext_vector_type(8)));
typedef unsigned short ushort8_t __attribute__((ext_vector_type(8)));
typedef float floatx16 __attribute__((ext_vector_type(16)));
typedef float f32x4 __attribute__((ext_vector_type(4)));

// LDS feature-tile row stride (f16 elems): 400 B rows, 16B-aligned.
constexpr int FS = 200;

// d_ws layout (bytes), all 16B-aligned:
//   [0,     24576)  W1t f16 [64][192]   (transposed: [n][k])
//   [24576, 45056)  W2t f16 [64][160]
//   [45056, 46080)  ub  f16 [16][32]
//   [46080, ...  )  xb  f16 [100000][64]  (12.8 MB)
// agg (f16 [100000][64]) lives INSIDE d_out: row n occupies the first
// 128 B of out row n (256 B). Block-exclusive in node_kernel -> no race.
constexpr size_t WS_W1T = 0;
constexpr size_t WS_W2T = 24576;
constexpr size_t WS_UB  = 45056;
constexpr size_t WS_XB  = 46080;

__device__ inline unsigned pack_f2(float a, float b) {
    auto h = __builtin_amdgcn_cvt_pkrtz(a, b);    // v_cvt_pkrtz_f16_f32
    return __builtin_bit_cast(unsigned, h);
}

// Wave-synchronous LDS fence: all of this wave's outstanding LDS ops done.
__device__ inline void wave_lds_fence() {
    asm volatile("s_waitcnt lgkmcnt(0)" ::: "memory");
}

// ---------------------------------------------------------------------------
// Prep: f16-convert x, u; f16+transpose W1, W2; zero d_out (agg accumulator).
// ---------------------------------------------------------------------------
__global__ __launch_bounds__(256) void prep_kernel(
    const float* __restrict__ x, const float* __restrict__ u,
    const float* __restrict__ W1, const float* __restrict__ W2,
    unsigned short* __restrict__ ws_w1t, unsigned short* __restrict__ ws_w2t,
    unsigned short* __restrict__ ws_ub, unsigned short* __restrict__ ws_xb,
    float* __restrict__ out)
{
    const int t = blockIdx.x * 256 + threadIdx.x;
    const int stride = gridDim.x * 256;
    const float4* x4 = (const float4*)x;
    for (int i = t; i < N_NODES * 16; i += stride) {       // x: 1.6M float4
        float4 v = x4[i];
        uint2 pk;
        pk.x = pack_f2(v.x, v.y);
        pk.y = pack_f2(v.z, v.w);
        *(uint2*)&ws_xb[i * 4] = pk;
    }
    const uint4 z = {0, 0, 0, 0};
    uint4* o4 = (uint4*)out;
    for (int i = t; i < N_NODES * 16; i += stride)         // zero agg/out
        o4[i] = z;
    for (int i = t; i < K1 * 64; i += stride) {            // W1 [k][n] -> [n][k]
        int k = i >> 6, n = i & 63;
        _Float16 h = (_Float16)W1[i];
        ws_w1t[n * K1 + k] = __builtin_bit_cast(unsigned short, h);
    }
    for (int i = t; i < K2 * 64; i += stride) {            // W2 [k][n] -> [n][k]
        int k = i >> 6, n = i & 63;
        _Float16 h = (_Float16)W2[i];
        ws_w2t[n * K2 + k] = __builtin_bit_cast(unsigned short, h);
    }
    for (int i = t; i < 16 * D_GLOB; i += stride) {        // u
        _Float16 h = (_Float16)u[i];
        ws_ub[i] = __builtin_bit_cast(unsigned short, h);
    }
}

// ---------------------------------------------------------------------------
// Edge kernel, BARRIER-FREE: one 16-edge tile per WAVE (16x16x32 MFMA).
// Each wave owns a private LDS segment (feat 16 x FS f16, overlaid by msg
// f32 [16][64]) and its own 16 indices -> zero __syncthreads; intra-wave
// LDS exchange ordered by s_waitcnt lgkmcnt(0). 24 independent latency
// streams per CU (vs 6 lock-stepped 4-wave groups before).
// Per K-step: A = feat rows (edge = lane&15, k = (lane>>4)*8+j),
// B = W1t rows (ch = g*16 + (lane&15)) read from L1-hot global (24 KB).
// D[edge][ch]: ch = lane&15, edge = (lane>>4)*4 + r.
// Epilogue: msg via LDS transpose, pk_add_f16, 2 agg rows per instr
// (locality identical to the proven R5 epilogue; same 32M total ops).
// ---------------------------------------------------------------------------
__global__ __launch_bounds__(256, 6) void edge_kernel(
    const unsigned short* __restrict__ xb, const int* __restrict__ ei,
    const float* __restrict__ ea, const unsigned short* __restrict__ ub,
    const int* __restrict__ batch, const unsigned short* __restrict__ W1t,
    const float* __restrict__ b1, float* __restrict__ out)
{
    __shared__ __align__(16) unsigned short feat[4][16 * FS]; // 4 x 6400 B
    __shared__ int s_idx[4][3][16];                           // dst/src/b

    const int tid  = threadIdx.x;
    const int lane = tid & 63;
    const int wv   = tid >> 6;
    const int t0   = blockIdx.x * 64 + wv * 16;   // this wave's 16 edges
    const float4* ea4 = (const float4*)ea;

    unsigned short* fseg = feat[wv];

    // ea chunks are index-independent: issue first. 64 lanes = 16 edges x 4.
    {
        int el = lane >> 2, c = lane & 3;
        float4 v0 = ea4[(size_t)(t0 + el) * 8 + c * 2 + 0];
        float4 v1 = ea4[(size_t)(t0 + el) * 8 + c * 2 + 1];
        uint4 pk;
        pk.x = pack_f2(v0.x, v0.y); pk.y = pack_f2(v0.z, v0.w);
        pk.z = pack_f2(v1.x, v1.y); pk.w = pack_f2(v1.z, v1.w);
        *(uint4*)&fseg[el * FS + (16 + c) * 8] = pk;
    }

    // Index chain (lane<16): dst -> src, batch[dst]; into wave's LDS.
    if (lane < 16) {
        int e = t0 + lane;
        int d = ei[N_EDGES + e];
        s_idx[wv][0][lane] = d;
        s_idx[wv][1][lane] = ei[e];
        s_idx[wv][2][lane] = batch[d];
    }
    wave_lds_fence();                      // idx + ea writes visible in-wave

    // Gather 20 chunks/edge (x[dst]:8 | x[src]:8 | u:4), 5 per lane.
    // K slots: x_dst [0,64), x_src [64,128), ea [128,160), u [160,192).
    for (int q = lane; q < 16 * 20; q += 64) {
        int el = q / 20;
        int c  = q - el * 20;
        uint4 pk;
        if (c < 8)       pk = *(const uint4*)&xb[(size_t)s_idx[wv][0][el] * 64 + c * 8];
        else if (c < 16) pk = *(const uint4*)&xb[(size_t)s_idx[wv][1][el] * 64 + (c - 8) * 8];
        else             pk = *(const uint4*)&ub[s_idx[wv][2][el] * 32 + (c - 16) * 8];
        *(uint4*)&fseg[el * FS + (c < 16 ? c : c + 4) * 8] = pk;
    }
    wave_lds_fence();                      // feat complete

    // MFMA: 6 K-steps x 4 channel groups; B re-read from L1-hot W1t.
    const int arow = lane & 15;            // A: edge row / B: channel-in-group
    const int kb   = lane >> 4;            // k sub-block 0..3 (k = kb*8 + j)
    f32x4 acc[4] = {{0,0,0,0}, {0,0,0,0}, {0,0,0,0}, {0,0,0,0}};
    #pragma unroll
    for (int ks = 0; ks < 6; ++ks) {
        f16x8 a = __builtin_bit_cast(f16x8,
            *(const ushort8_t*)&fseg[arow * FS + ks * 32 + kb * 8]);
        #pragma unroll
        for (int g = 0; g < 4; ++g) {
            f16x8 b = __builtin_bit_cast(f16x8,
                *(const ushort8_t*)&W1t[(g * 16 + arow) * K1 + ks * 32 + kb * 8]);
            acc[g] = __builtin_amdgcn_mfma_f32_16x16x32_f16(a, b, acc[g], 0, 0, 0);
        }
    }
    wave_lds_fence();                      // all feat reads drained (WAR)

    // Stage msg f32 [16 edge][64 ch] over the feat segment.
    float* mseg = (float*)fseg;            // 4096 B <= 6400 B
    #pragma unroll
    for (int g = 0; g < 4; ++g)
        #pragma unroll
        for (int r = 0; r < 4; ++r)
            mseg[((lane >> 4) * 4 + r) * 64 + g * 16 + (lane & 15)] = acc[g][r];
    wave_lds_fence();                      // msg visible in-wave

    // Transposed epilogue: per iter, 64 lanes cover 2 edge rows x 32
    // channel-pairs -> 2 agg rows (2 lines each), pk_add_f16.
    const int chp = (lane & 31) * 2;
    const float2 bv = *(const float2*)&b1[chp];
    #pragma unroll
    for (int it = 0; it < 8; ++it) {
        int el = it * 2 + (lane >> 5);
        float2 m = *(const float2*)&mseg[el * 64 + chp];
        float v0 = m.x + bv.x; v0 = v0 > 0.f ? v0 : 0.f;
        float v1 = m.y + bv.y; v1 = v1 > 0.f ? v1 : 0.f;
        unsigned pk = pack_f2(v0, v1);
        unsigned short* p = (unsigned short*)out + (size_t)s_idx[wv][0][el] * 128 + chp;
        asm volatile("global_atomic_pk_add_f16 %0, %1, off"
                     :: "v"(p), "v"(pk) : "memory");
    }
}

// ---------------------------------------------------------------------------
// Node kernel (32x32x16 MFMA): out = relu([x, agg, u[batch]] @ W2 + b2)
// agg read f16 from the first 128 B of each out row; in-place, row-exclusive
// per block. One 64-node tile per block (tail guarded).
// ---------------------------------------------------------------------------
__global__ __launch_bounds__(256, 6) void node_kernel(
    const unsigned short* __restrict__ xb, const unsigned short* __restrict__ ub,
    const int* __restrict__ batch, const unsigned short* __restrict__ W2t,
    const float* __restrict__ b2, float* __restrict__ out)
{
    __shared__ __align__(16) unsigned short smem[64 * FS];
    __shared__ int s_b[64];

    const int tid  = threadIdx.x;
    const int lane = tid & 63;
    const int wv   = tid >> 6;
    const int base = blockIdx.x * 64;
    const int eh   = wv >> 1;
    const int nh   = wv & 1;
    const int col  = lane & 31;
    const int half = lane >> 5;

    if (tid < 64) {
        int n = base + tid;
        s_b[tid] = (n < N_NODES) ? batch[n] : 0;
    }

    f16x8 Bf[10];
    #pragma unroll
    for (int s = 0; s < 10; ++s)
        Bf[s] = __builtin_bit_cast(f16x8,
            *(const ushort8_t*)&W2t[(nh*32 + col) * K2 + s*16 + half*8]);
    const float b2v = b2[nh*32 + col];

    __syncthreads();

    // Gather: 64 nodes x 20 16B-chunks (x:8 | agg:8 | u:4)
    const unsigned short* aggb = (const unsigned short*)out;
    for (int q = tid; q < 64 * 20; q += 256) {
        int nl = q / 20;
        int c  = q - nl * 20;
        int n  = base + nl;
        uint4 pk;
        if (n >= N_NODES) pk = uint4{0, 0, 0, 0};
        else if (c < 8)   pk = *(const uint4*)&xb[n * 64 + c * 8];
        else if (c < 16)  pk = *(const uint4*)&aggb[(size_t)n * 128 + (c - 8) * 8];
        else              pk = *(const uint4*)&ub[s_b[nl] * 32 + (c - 16) * 8];
        *(uint4*)&smem[nl * FS + c * 8] = pk;
    }
    __syncthreads();

    floatx16 acc = {0,0,0,0,0,0,0,0,0,0,0,0,0,0,0,0};
    #pragma unroll
    for (int s = 0; s < 10; ++s) {
        f16x8 a = __builtin_bit_cast(f16x8,
            *(const ushort8_t*)&smem[(eh*32 + col) * FS + s*16 + half*8]);
        acc = __builtin_amdgcn_mfma_f32_32x32x16_f16(a, Bf[s], acc, 0, 0, 0);
    }

    #pragma unroll
    for (int r = 0; r < 16; ++r) {
        int n = base + eh*32 + (r & 3) + 8*(r >> 2) + 4*half;
        if (n < N_NODES) {
            float vv = acc[r] + b2v;
            out[n * 64 + nh*32 + col] = vv > 0.f ? vv : 0.f;
        }
    }
}

extern "C" void kernel_launch(void* const* d_in, const int* in_sizes, int n_in,
                              void* d_out, int out_size, void* d_ws, size_t ws_size,
                              hipStream_t stream) {
    const float* x     = (const float*)d_in[0];
    const int*   ei    = (const int*)d_in[1];
    const float* ea    = (const float*)d_in[2];
    const float* u     = (const float*)d_in[3];
    const int*   batch = (const int*)d_in[4];
    const float* W1    = (const float*)d_in[5];
    const float* b1    = (const float*)d_in[6];
    const float* W2    = (const float*)d_in[7];
    const float* b2    = (const float*)d_in[8];
    float* out = (float*)d_out;

    unsigned short* ws_w1t = (unsigned short*)((char*)d_ws + WS_W1T);
    unsigned short* ws_w2t = (unsigned short*)((char*)d_ws + WS_W2T);
    unsigned short* ws_ub  = (unsigned short*)((char*)d_ws + WS_UB);
    unsigned short* ws_xb  = (unsigned short*)((char*)d_ws + WS_XB);

    // prep also zeroes d_out (agg f16 accumulator lives in its low halves)
    prep_kernel<<<2048, 256, 0, stream>>>(x, u, W1, W2, ws_w1t, ws_w2t,
                                          ws_ub, ws_xb, out);
    edge_kernel<<<N_EDGES / 64, 256, 0, stream>>>(ws_xb, ei, ea, ws_ub, batch, ws_w1t, b1, out);
    node_kernel<<<(N_NODES + 63) / 64, 256, 0, stream>>>(ws_xb, ws_ub, batch, ws_w2t, b2, out);
}